// Round 13
// baseline (117.539 us; speedup 1.0000x reference)
//
#include <hip/hip_runtime.h>

// Undistort (inverse radial distortion resample), C=3, H=W=2048, fp32.
// rd*cos(theta) == xur/(1-k*ru^2), rd*sin(theta) == yur/(1-k*ru^2):
// coordinate map = FMAs + one fast reciprocal (no sqrt/atan2/sincos).
//
// Structure (established R2-R6): channel-split grid (12288 blocks),
// lane-consecutive x (wave spans 256 consecutive x, 4 px/thread strided
// by 64), deep VMEM batches, nontemporal stores, bijective XCD swizzle.
//
// R6 finding: time tracks total VMEM wave-instruction count (~26-32
// cyc/instr), not lines/BW/occupancy/TLP. R10 (memcpy-based unaligned
// 8B paired-tap loads) was only +8%, ambiguous: either the compiler
// split the loads (still 20 VMEM/thread) or the count model is wrong.
// R11/R12: force guaranteed global_load_dwordx2 via inline asm ->
// exactly 12 VMEM/thread (8 paired-tap gathers + 4 stores). Batch-issue
// all 8, one s_waitcnt vmcnt(0) with "+v" ties so no use precedes it.
// Edge semantics identical to R10 (proven): pair base clamp [0, W-2];
// xfi>=W-1 selects pair.y for tap0; pairs never cross a row end.

#define UND_C 3
#define UND_H 2048
#define UND_W 2048
#define PLANE (UND_H * UND_W)

__global__ __launch_bounds__(256, 4) void undistort_kernel(
    const float* __restrict__ im,   // [C][H][W]
    const float* __restrict__ kp,
    const float* __restrict__ dxp,
    const float* __restrict__ dyp,
    float* __restrict__ out)        // [C][H][W]
{
    constexpr int W = UND_W, H = UND_H;
    constexpr int NWG = UND_C * 8 * (H / 4);   // 12288
    constexpr int PER_XCD = NWG / 8;           // 1536 (bijective: NWG%8==0)

    // XCD-aware swizzle: each XCD owns a contiguous chunk of (ch,tile) space.
    const int b  = blockIdx.x;
    const int bs = (b & 7) * PER_XCD + (b >> 3);
    const int ch = bs >> 12;          // /4096 tiles per channel
    const int t  = bs & 4095;
    const int bx = t & 7;             // 8 x-tiles of 256 px
    const int by = t >> 3;            // 512 y-tiles of 4 rows

    const int lane = threadIdx.x & 63;
    const int wid  = threadIdx.x >> 6;
    const int x0   = bx * 256 + lane;          // lane-consecutive x
    const int y    = by * 4 + wid;

    const float k  = kp[0];
    const float dx = dxp[0];
    const float dy = dyp[0];

    const float yur  = ((float)y - dy) * (1.0f / (float)H) - 0.5f;
    const float yur2 = yur * yur;

    float w00[4], w01[4], w10[4], w11[4];
    int   offf[4], offc[4];
    bool  hi[4], valid[4];

#pragma unroll
    for (int j = 0; j < 4; ++j) {
        const int   x   = x0 + 64 * j;
        const float xur = ((float)x - dx) * (1.0f / (float)W) - 0.5f;
        const float r2  = xur * xur + yur2;
        const float s   = __builtin_amdgcn_rcpf(1.0f - k * r2);  // rd/ru

        const float xd = (xur * s + 0.5f) * (float)W + dx;
        const float yd = (yur * s + 0.5f) * (float)H + dy;

        const float xf = floorf(xd);
        const float yf = floorf(yd);

        const float ox  = xd - xf;
        const float oy  = yd - yf;
        const float onx = 1.0f - ox;
        const float ony = 1.0f - oy;

        // ceil(xd) < W  <=>  xd <= W-1 ; likewise for y.
        valid[j] = (xf >= 0.0f) & (xd <= (float)(W - 1)) &
                   (yf >= 0.0f) & (yd <= (float)(H - 1));

        int xfi = (int)xf;
        int yfi = (int)yf; yfi = yfi < 0 ? 0 : (yfi > H - 1 ? H - 1 : yfi);
        const int yci = yfi + 1 > H - 1 ? H - 1 : yfi + 1;

        hi[j] = xfi >= W - 1;                       // tap0 = pair.y there
        int xp = xfi < 0 ? 0 : (xfi > W - 2 ? W - 2 : xfi);  // pair base

        offf[j] = yfi * W + xp;
        offc[j] = yci * W + xp;

        w00[j] = onx * ony;
        w01[j] = ox * ony;
        w10[j] = onx * oy;
        w11[j] = ox * oy;
    }

    const float* __restrict__ p = im + (size_t)ch * PLANE;

    // 8 guaranteed-dwordx2 paired-tap gathers, batch-issued.
    float2 vf[4], vc[4];
#pragma unroll
    for (int j = 0; j < 4; ++j) {
        const float* a = p + offf[j];
        asm volatile("global_load_dwordx2 %0, %1, off"
                     : "=v"(vf[j]) : "v"(a));
    }
#pragma unroll
    for (int j = 0; j < 4; ++j) {
        const float* a = p + offc[j];
        asm volatile("global_load_dwordx2 %0, %1, off"
                     : "=v"(vc[j]) : "v"(a));
    }
    // Single drain; "+v" ties make every consumer data-dependent on it.
    asm volatile("s_waitcnt vmcnt(0)"
                 : "+v"(vf[0]), "+v"(vf[1]), "+v"(vf[2]), "+v"(vf[3]),
                   "+v"(vc[0]), "+v"(vc[1]), "+v"(vc[2]), "+v"(vc[3]));
    __builtin_amdgcn_sched_barrier(0);

    float* __restrict__ po = out + (size_t)ch * PLANE + y * W + x0;
#pragma unroll
    for (int j = 0; j < 4; ++j) {
        const float v00 = hi[j] ? vf[j].y : vf[j].x;
        const float v10 = hi[j] ? vc[j].y : vc[j].x;
        float acc = w00[j] * v00 + w01[j] * vf[j].y
                  + w10[j] * v10 + w11[j] * vc[j].y;
        __builtin_nontemporal_store(valid[j] ? acc : 0.0f, po + 64 * j);
    }
}

extern "C" void kernel_launch(void* const* d_in, const int* in_sizes, int n_in,
                              void* d_out, int out_size, void* d_ws, size_t ws_size,
                              hipStream_t stream) {
    (void)in_sizes; (void)n_in; (void)d_ws; (void)ws_size; (void)out_size;
    const float* im = (const float*)d_in[0];
    const float* k  = (const float*)d_in[1];
    const float* dx = (const float*)d_in[2];
    const float* dy = (const float*)d_in[3];
    float* out = (float*)d_out;

    constexpr int NWG = UND_C * 8 * (UND_H / 4);  // 12288
    undistort_kernel<<<NWG, 256, 0, stream>>>(im, k, dx, dy, out);
}

// Round 14
// 117.274 us; speedup vs baseline: 1.0023x; 1.0023x over previous
//
#include <hip/hip_runtime.h>

// Undistort (inverse radial distortion resample), C=3, H=W=2048, fp32.
// rd*cos(theta) == xur/(1-k*ru^2), rd*sin(theta) == yur/(1-k*ru^2):
// coordinate map = FMAs + one fast reciprocal (no sqrt/atan2/sincos).
//
// Ladder so far: lane-consecutive x (R4, -25%), channel-split TLP (R6,
// neutral), paired-tap 8B gathers (R10 +8%), forced dwordx2 (R13,
// neutral vs R10) -> per-INSTRUCTION model refuted; cost tracks either
// total gathered dwords (TA lane-dword rate ~4/cyc/CU -> ~26us floor)
// or per-wave miss concurrency (8 in flight, full drain each time).
//
// R14 discriminates: 8 px/thread, TWO load groups with counted drains:
// issue 16 x2-gathers (A then B), vmcnt(8) -> consume A (+4 stores),
// vmcnt(4) -> consume B (A-stores issued after B-loads, so <=4 means
// all B loads returned). 2x outstanding misses/wave, 0.5x waves.
// Edge semantics (proven R10/R13): pair base clamp [0,W-2]; xfi>=W-1
// selects pair.y for tap0; pairs never cross a row end; invalid masked.

#define UND_C 3
#define UND_H 2048
#define UND_W 2048
#define PLANE (UND_H * UND_W)

__global__ __launch_bounds__(256, 4) void undistort_kernel(
    const float* __restrict__ im,   // [C][H][W]
    const float* __restrict__ kp,
    const float* __restrict__ dxp,
    const float* __restrict__ dyp,
    float* __restrict__ out)        // [C][H][W]
{
    constexpr int W = UND_W, H = UND_H;
    constexpr int NWG = UND_C * 4 * (H / 4);   // 6144
    constexpr int PER_XCD = NWG / 8;           // 768 (bijective: NWG%8==0)

    // XCD-aware swizzle: each XCD owns a contiguous chunk of (ch,tile) space.
    const int b  = blockIdx.x;
    const int bs = (b & 7) * PER_XCD + (b >> 3);
    const int ch = bs >> 11;          // /2048 tiles per channel
    const int t  = bs & 2047;
    const int bx = t & 3;             // 4 x-tiles of 512 px
    const int by = t >> 2;            // 512 y-tiles of 4 rows

    const int lane = threadIdx.x & 63;
    const int wid  = threadIdx.x >> 6;
    const int x0   = bx * 512 + lane;          // lane-consecutive x
    const int y    = by * 4 + wid;

    const float k  = kp[0];
    const float dx = dxp[0];
    const float dy = dyp[0];

    const float yur  = ((float)y - dy) * (1.0f / (float)H) - 0.5f;
    const float yur2 = yur * yur;

    float w00[8], w01[8], w10[8], w11[8];
    int   offf[8], offc[8];
    bool  hi[8], valid[8];

#pragma unroll
    for (int j = 0; j < 8; ++j) {
        const int   x   = x0 + 64 * j;
        const float xur = ((float)x - dx) * (1.0f / (float)W) - 0.5f;
        const float r2  = xur * xur + yur2;
        const float s   = __builtin_amdgcn_rcpf(1.0f - k * r2);  // rd/ru

        const float xd = (xur * s + 0.5f) * (float)W + dx;
        const float yd = (yur * s + 0.5f) * (float)H + dy;

        const float xf = floorf(xd);
        const float yf = floorf(yd);

        const float ox  = xd - xf;
        const float oy  = yd - yf;
        const float onx = 1.0f - ox;
        const float ony = 1.0f - oy;

        // ceil(xd) < W  <=>  xd <= W-1 ; likewise for y.
        valid[j] = (xf >= 0.0f) & (xd <= (float)(W - 1)) &
                   (yf >= 0.0f) & (yd <= (float)(H - 1));

        int xfi = (int)xf;
        int yfi = (int)yf; yfi = yfi < 0 ? 0 : (yfi > H - 1 ? H - 1 : yfi);
        const int yci = yfi + 1 > H - 1 ? H - 1 : yfi + 1;

        hi[j] = xfi >= W - 1;                       // tap0 = pair.y there
        int xp = xfi < 0 ? 0 : (xfi > W - 2 ? W - 2 : xfi);  // pair base

        offf[j] = yfi * W + xp;
        offc[j] = yci * W + xp;

        w00[j] = onx * ony;
        w01[j] = ox * ony;
        w10[j] = onx * oy;
        w11[j] = ox * oy;
    }

    const float* __restrict__ p = im + (size_t)ch * PLANE;
    float* __restrict__ po = out + (size_t)ch * PLANE + y * W + x0;

    // Group A (j=0..3): 8 x2-gathers.  Group B (j=4..7): 8 x2-gathers.
    float2 vfA[4], vcA[4], vfB[4], vcB[4];
#pragma unroll
    for (int j = 0; j < 4; ++j) {
        const float* a = p + offf[j];
        asm volatile("global_load_dwordx2 %0, %1, off" : "=v"(vfA[j]) : "v"(a));
    }
#pragma unroll
    for (int j = 0; j < 4; ++j) {
        const float* a = p + offc[j];
        asm volatile("global_load_dwordx2 %0, %1, off" : "=v"(vcA[j]) : "v"(a));
    }
#pragma unroll
    for (int j = 0; j < 4; ++j) {
        const float* a = p + offf[j + 4];
        asm volatile("global_load_dwordx2 %0, %1, off" : "=v"(vfB[j]) : "v"(a));
    }
#pragma unroll
    for (int j = 0; j < 4; ++j) {
        const float* a = p + offc[j + 4];
        asm volatile("global_load_dwordx2 %0, %1, off" : "=v"(vcB[j]) : "v"(a));
    }

    // Drain to 8 outstanding: group A returned, group B still in flight.
    asm volatile("s_waitcnt vmcnt(8)"
                 : "+v"(vfA[0]), "+v"(vfA[1]), "+v"(vfA[2]), "+v"(vfA[3]),
                   "+v"(vcA[0]), "+v"(vcA[1]), "+v"(vcA[2]), "+v"(vcA[3]));
    __builtin_amdgcn_sched_barrier(0);

#pragma unroll
    for (int j = 0; j < 4; ++j) {
        const float v00 = hi[j] ? vfA[j].y : vfA[j].x;
        const float v10 = hi[j] ? vcA[j].y : vcA[j].x;
        float acc = w00[j] * v00 + w01[j] * vfA[j].y
                  + w10[j] * v10 + w11[j] * vcA[j].y;
        __builtin_nontemporal_store(valid[j] ? acc : 0.0f, po + 64 * j);
    }

    // A-stores were issued AFTER B-loads; vmcnt(4) -> all B loads done
    // (up to 4 stores may remain outstanding, which is fine).
    asm volatile("s_waitcnt vmcnt(4)"
                 : "+v"(vfB[0]), "+v"(vfB[1]), "+v"(vfB[2]), "+v"(vfB[3]),
                   "+v"(vcB[0]), "+v"(vcB[1]), "+v"(vcB[2]), "+v"(vcB[3]));
    __builtin_amdgcn_sched_barrier(0);

#pragma unroll
    for (int j = 0; j < 4; ++j) {
        const float v00 = hi[j + 4] ? vfB[j].y : vfB[j].x;
        const float v10 = hi[j + 4] ? vcB[j].y : vcB[j].x;
        float acc = w00[j + 4] * v00 + w01[j + 4] * vfB[j].y
                  + w10[j + 4] * v10 + w11[j + 4] * vcB[j].y;
        __builtin_nontemporal_store(valid[j + 4] ? acc : 0.0f, po + 64 * (j + 4));
    }
}

extern "C" void kernel_launch(void* const* d_in, const int* in_sizes, int n_in,
                              void* d_out, int out_size, void* d_ws, size_t ws_size,
                              hipStream_t stream) {
    (void)in_sizes; (void)n_in; (void)d_ws; (void)ws_size; (void)out_size;
    const float* im = (const float*)d_in[0];
    const float* k  = (const float*)d_in[1];
    const float* dx = (const float*)d_in[2];
    const float* dy = (const float*)d_in[3];
    float* out = (float*)d_out;

    constexpr int NWG = UND_C * 4 * (UND_H / 4);  // 6144
    undistort_kernel<<<NWG, 256, 0, stream>>>(im, k, dx, dy, out);
}